// Round 1
// baseline (302.897 us; speedup 1.0000x reference)
//
#include <hip/hip_runtime.h>
#include <math.h>

#define N 4096
#define D 512
#define NCLASS 31

// ws layout (floats):
// sq:      [0, 4096)
// denom:   [4096, 8192)
// S:       [8192, 12288)
// colsum:  [12288, 12800)
// sumsq:   [12800]
// bw:      [12801]
// cnt:     [12802, 12834)  (ints)
constexpr int WS_FLOATS = 12802 + 32;

// ---------------- row squared norms + total ----------------
__global__ __launch_bounds__(256) void rowsq_kernel(const float* __restrict__ X,
                                                    float* __restrict__ sq,
                                                    float* __restrict__ sumsq) {
    int wave = threadIdx.x >> 6;
    int lane = threadIdx.x & 63;
    int row = blockIdx.x * 4 + wave;
    const float4* p = (const float4*)(X + (size_t)row * D);
    float4 v0 = p[lane * 2];
    float4 v1 = p[lane * 2 + 1];
    float s = v0.x * v0.x + v0.y * v0.y + v0.z * v0.z + v0.w * v0.w
            + v1.x * v1.x + v1.y * v1.y + v1.z * v1.z + v1.w * v1.w;
    #pragma unroll
    for (int m = 32; m; m >>= 1) s += __shfl_xor(s, m);
    if (lane == 0) {
        sq[row] = s;
        atomicAdd(sumsq, s);
    }
}

// ---------------- column sums (for ||sum_i x_i||^2) ----------------
__global__ __launch_bounds__(256) void colsum_kernel(const float* __restrict__ X,
                                                     float* __restrict__ colsum) {
    int c0 = threadIdx.x;
    int c1 = threadIdx.x + 256;
    int r0 = blockIdx.x * 64;
    float s0 = 0.f, s1 = 0.f;
    for (int r = r0; r < r0 + 64; r++) {
        s0 += X[(size_t)r * D + c0];
        s1 += X[(size_t)r * D + c1];
    }
    atomicAdd(&colsum[c0], s0);
    atomicAdd(&colsum[c1], s1);
}

// ---------------- label histogram ----------------
__global__ __launch_bounds__(256) void hist_kernel(const int* __restrict__ lab,
                                                   int* __restrict__ cnt) {
    int i = blockIdx.x * 256 + threadIdx.x;
    if (i < N) atomicAdd(&cnt[lab[i]], 1);
}

// ---------------- bandwidth ----------------
__global__ __launch_bounds__(64) void bw_kernel(const float* __restrict__ colsum,
                                                const float* __restrict__ sumsq,
                                                float* __restrict__ bw) {
    int lane = threadIdx.x;
    float s = 0.f;
    for (int k = lane; k < D; k += 64) {
        float v = colsum[k];
        s += v * v;
    }
    #pragma unroll
    for (int m = 32; m; m >>= 1) s += __shfl_xor(s, m);
    if (lane == 0) {
        // sum(L2) = 2*N*sum_i ||x_i||^2 - 2*||sum_i x_i||^2
        double total = 2.0 * (double)N * (double)(*sumsq) - 2.0 * (double)s;
        double b = total / ((double)N * (double)N - (double)N);
        b = b / 4.0;  // KERNEL_MUL^(KERNEL_NUM//2) = 2^2
        *bw = (float)b;
    }
}

// ---------------- fused Gram GEMM + RBF + contrastive row stats ----------------
constexpr int BM = 128, BN = 128, BK = 16;

__global__ __launch_bounds__(256) void gemm_fused_kernel(const float* __restrict__ X,
                                                         const int* __restrict__ lab,
                                                         const float* __restrict__ sq,
                                                         const float* __restrict__ bwp,
                                                         float* __restrict__ denom,
                                                         float* __restrict__ Ssum) {
    __shared__ float As[BK][BM];
    __shared__ float Bs[BK][BN];
    const int tid = threadIdx.x;
    const int nbx = N / BN;  // 32
    const int bx = blockIdx.x % nbx;
    const int by = blockIdx.x / nbx;
    const int rowBase = by * BM, colBase = bx * BN;
    // staging: thread loads 8 floats of one tile-row (2 x float4)
    const int lr = tid >> 1;
    const int lc = (tid & 1) * 8;
    const float* Ap = X + (size_t)(rowBase + lr) * D + lc;
    const float* Bp = X + (size_t)(colBase + lr) * D + lc;
    const int ty = tid >> 4, tx = tid & 15;

    float acc[8][8];
    #pragma unroll
    for (int i = 0; i < 8; i++)
        #pragma unroll
        for (int j = 0; j < 8; j++) acc[i][j] = 0.f;

    for (int k0 = 0; k0 < D; k0 += BK) {
        float4 a0 = *(const float4*)(Ap + k0);
        float4 a1 = *(const float4*)(Ap + k0 + 4);
        float4 b0 = *(const float4*)(Bp + k0);
        float4 b1 = *(const float4*)(Bp + k0 + 4);
        __syncthreads();  // previous tile fully consumed
        As[lc + 0][lr] = a0.x; As[lc + 1][lr] = a0.y;
        As[lc + 2][lr] = a0.z; As[lc + 3][lr] = a0.w;
        As[lc + 4][lr] = a1.x; As[lc + 5][lr] = a1.y;
        As[lc + 6][lr] = a1.z; As[lc + 7][lr] = a1.w;
        Bs[lc + 0][lr] = b0.x; Bs[lc + 1][lr] = b0.y;
        Bs[lc + 2][lr] = b0.z; Bs[lc + 3][lr] = b0.w;
        Bs[lc + 4][lr] = b1.x; Bs[lc + 5][lr] = b1.y;
        Bs[lc + 6][lr] = b1.z; Bs[lc + 7][lr] = b1.w;
        __syncthreads();
        #pragma unroll
        for (int kk = 0; kk < BK; kk++) {
            float a[8], b[8];
            *(float4*)&a[0] = *(const float4*)&As[kk][ty * 8];
            *(float4*)&a[4] = *(const float4*)&As[kk][ty * 8 + 4];
            *(float4*)&b[0] = *(const float4*)&Bs[kk][tx * 8];
            *(float4*)&b[4] = *(const float4*)&Bs[kk][tx * 8 + 4];
            #pragma unroll
            for (int i = 0; i < 8; i++)
                #pragma unroll
                for (int j = 0; j < 8; j++)
                    acc[i][j] = fmaf(a[i], b[j], acc[i][j]);
        }
    }

    // epilogue: L2 -> kernels -> logits -> row stats
    const float bw = *bwp;
    const float inv0 = 1.0f / bw;
    const float invb[5] = {inv0, inv0 * 0.5f, inv0 * 0.25f, inv0 * 0.125f, inv0 * 0.0625f};
    constexpr float INV_T = 1.0f / 0.35f;  // 1/(TEMPERATURE*KERNEL_NUM)

    float sqR[8], sqC[8];
    int labR[8], labC[8];
    #pragma unroll
    for (int i = 0; i < 8; i++) {
        int r = rowBase + ty * 8 + i;
        sqR[i] = sq[r];
        labR[i] = lab[r];
    }
    #pragma unroll
    for (int j = 0; j < 8; j++) {
        int c = colBase + tx * 8 + j;
        sqC[j] = sq[c];
        labC[j] = lab[c];
    }

    #pragma unroll
    for (int i = 0; i < 8; i++) {
        int r = rowBase + ty * 8 + i;
        float dAcc = 0.f, sAcc = 0.f;
        #pragma unroll
        for (int j = 0; j < 8; j++) {
            int c = colBase + tx * 8 + j;
            float L2 = fmaxf(sqR[i] + sqC[j] - 2.0f * acc[i][j], 0.0f);
            float kern = 0.f;
            #pragma unroll
            for (int m = 0; m < 5; m++) kern += __expf(-L2 * invb[m]);
            float logit = (kern - 5.0f) * INV_T;  // = a_ij - 1/0.07 (shift-invariant)
            if (r != c) {
                dAcc += __expf(logit);
                if (labR[i] == labC[j]) sAcc += logit;
            }
        }
        // reduce across the 16 tx-lanes sharing this row group
        #pragma unroll
        for (int m = 8; m; m >>= 1) {
            dAcc += __shfl_xor(dAcc, m);
            sAcc += __shfl_xor(sAcc, m);
        }
        if (tx == 0) {
            atomicAdd(&denom[r], dAcc);
            atomicAdd(&Ssum[r], sAcc);
        }
    }
}

// ---------------- finalize ----------------
__global__ __launch_bounds__(1024) void finalize_kernel(const float* __restrict__ denom,
                                                        const float* __restrict__ Ssum,
                                                        const int* __restrict__ lab,
                                                        const int* __restrict__ cnt,
                                                        float* __restrict__ out) {
    int tid = threadIdx.x;
    float lsum = 0.f, vcnt = 0.f;
    for (int r = tid; r < N; r += 1024) {
        int P = cnt[lab[r]] - 1;
        if (P > 0) {
            float fl = (float)P;
            float mean = (Ssum[r] - fl * logf(denom[r])) / fl;
            lsum -= mean;  // -(T/BASE_T)=-1 times mean
            vcnt += 1.f;
        }
    }
    __shared__ float s1[16], s2[16];
    int lane = tid & 63, wv = tid >> 6;
    #pragma unroll
    for (int m = 32; m; m >>= 1) {
        lsum += __shfl_xor(lsum, m);
        vcnt += __shfl_xor(vcnt, m);
    }
    if (lane == 0) { s1[wv] = lsum; s2[wv] = vcnt; }
    __syncthreads();
    if (wv == 0) {
        float a = (lane < 16) ? s1[lane] : 0.f;
        float b = (lane < 16) ? s2[lane] : 0.f;
        #pragma unroll
        for (int m = 8; m; m >>= 1) {
            a += __shfl_xor(a, m);
            b += __shfl_xor(b, m);
        }
        if (lane == 0) out[0] = a / fmaxf(b, 1.0f);
    }
}

extern "C" void kernel_launch(void* const* d_in, const int* in_sizes, int n_in,
                              void* d_out, int out_size, void* d_ws, size_t ws_size,
                              hipStream_t stream) {
    const float* X = (const float*)d_in[0];
    const int* lab = (const int*)d_in[1];
    float* ws = (float*)d_ws;
    float* sq = ws;
    float* denom = ws + 4096;
    float* Ssum = ws + 8192;
    float* colsum = ws + 12288;
    float* sumsq = ws + 12800;
    float* bw = ws + 12801;
    int* cnt = (int*)(ws + 12802);

    hipMemsetAsync(d_ws, 0, WS_FLOATS * sizeof(float), stream);
    rowsq_kernel<<<N / 4, 256, 0, stream>>>(X, sq, sumsq);
    colsum_kernel<<<N / 64, 256, 0, stream>>>(X, colsum);
    hist_kernel<<<(N + 255) / 256, 256, 0, stream>>>(lab, cnt);
    bw_kernel<<<1, 64, 0, stream>>>(colsum, sumsq, bw);
    gemm_fused_kernel<<<(N / BM) * (N / BN), 256, 0, stream>>>(X, lab, sq, bw, denom, Ssum);
    finalize_kernel<<<1, 1024, 0, stream>>>(denom, Ssum, lab, cnt, (float*)d_out);
}

// Round 2
// 114.455 us; speedup vs baseline: 2.6464x; 2.6464x over previous
//
#include <hip/hip_runtime.h>
#include <math.h>

#define N 4096
#define D 512
#define NCLASS 31

typedef unsigned short u16;
typedef unsigned int u32;
typedef short bf16x8 __attribute__((ext_vector_type(8)));
typedef float f32x4 __attribute__((ext_vector_type(4)));

__device__ __forceinline__ u32 f2bf(float x) {
    u32 u = __float_as_uint(x);
    return (u + 0x7FFFu + ((u >> 16) & 1u)) >> 16;  // RNE bf16 (no inf/nan in data)
}
__device__ __forceinline__ float bf2f(u32 h) {
    return __uint_as_float(h << 16);
}

__device__ __forceinline__ void gll16(const void* g, void* l) {
    __builtin_amdgcn_global_load_lds(
        (const __attribute__((address_space(1))) u32*)g,
        (__attribute__((address_space(3))) u32*)l, 16, 0, 0);
}

// ---------------- new-path ws layout (float units) ----------------
// hi (bf16 of X): N*D u16 = N*D/2 float slots
constexpr size_t HI_FLOATS  = (size_t)N * D / 2;            // 1048576
constexpr size_t OFF_SQH    = HI_FLOATS;                    // N
constexpr size_t OFF_DENOMP = OFF_SQH + N;                  // 64*N
constexpr size_t OFF_SP     = OFF_DENOMP + 64 * (size_t)N;  // 64*N
constexpr size_t OFF_COLSUM = OFF_SP + 64 * (size_t)N;      // D
constexpr size_t OFF_SUMSQ  = OFF_COLSUM + D;               // 1
constexpr size_t OFF_CNT    = OFF_SUMSQ + 1;                // NCLASS ints
constexpr size_t WS_NEED    = (OFF_CNT + NCLASS + 8) * 4;

// ============ prep: convert fp32->bf16 + colsum + sumsq + rowsq + hist ============
__global__ __launch_bounds__(256) void prep_kernel(const float* __restrict__ X,
                                                   const int* __restrict__ lab,
                                                   u16* __restrict__ hi,
                                                   float* __restrict__ sqh,
                                                   float* __restrict__ colsum,
                                                   float* __restrict__ sumsq,
                                                   int* __restrict__ cnt) {
    const int t = threadIdx.x;
    const int r0 = blockIdx.x * 64;
    float cs0 = 0.f, cs1 = 0.f, ss = 0.f;
    for (int r = r0; r < r0 + 64; r++) {
        float2 v = *(const float2*)(X + (size_t)r * D + t * 2);
        u32 h0 = f2bf(v.x), h1 = f2bf(v.y);
        *(u32*)(hi + (size_t)r * D + t * 2) = h0 | (h1 << 16);
        float q0 = bf2f(h0), q1 = bf2f(h1);
        cs0 += q0; cs1 += q1;
        ss += q0 * q0 + q1 * q1;
    }
    atomicAdd(&colsum[t * 2], cs0);
    atomicAdd(&colsum[t * 2 + 1], cs1);
    __shared__ float red[4];
    const int ln = t & 63, wv = t >> 6;
    #pragma unroll
    for (int m = 32; m; m >>= 1) ss += __shfl_xor(ss, m);
    if (ln == 0) red[wv] = ss;
    if (t < 64) atomicAdd(&cnt[lab[r0 + t]], 1);
    __syncthreads();
    if (t == 0) atomicAdd(sumsq, red[0] + red[1] + red[2] + red[3]);
    // per-row sq from hi (hi rows of this block written by this block; visible post-barrier)
    for (int i = 0; i < 16; i++) {
        int r = r0 + wv * 16 + i;
        bf16x8 v = *(const bf16x8*)(hi + (size_t)r * D + ln * 8);
        float s = 0.f;
        #pragma unroll
        for (int j = 0; j < 8; j++) { float f = bf2f((u16)v[j]); s += f * f; }
        #pragma unroll
        for (int m = 32; m; m >>= 1) s += __shfl_xor(s, m);
        if (ln == 0) sqh[r] = s;
    }
}

// ============ fused MFMA Gram + RBF + contrastive row stats ============
// 128x128 tile, 4 waves (2x2 quadrants of 64x64), 16x16x32 bf16 MFMA, BK=32.
// LDS layout is fragment-ordered: slot s (16B) holds row (s&127), kgroup (s>>7)
// -> ds_read_b128 of fragments is fully conflict-free, and global_load_lds's
// linear lane->slot mapping matches (per-lane global addr pre-permuted).
__global__ __launch_bounds__(256) void gemm_mfma_kernel(const u16* __restrict__ hi,
                                                        const int* __restrict__ lab,
                                                        const float* __restrict__ sqh,
                                                        const float* __restrict__ colsum,
                                                        const float* __restrict__ sumsq,
                                                        float* __restrict__ denomP,
                                                        float* __restrict__ SP) {
    __shared__ u16 As[128 * 32];
    __shared__ u16 Bs[128 * 32];
    __shared__ float bwS;
    const int tid = threadIdx.x;
    const int w = tid >> 6, l = tid & 63;
    const int bx = blockIdx.x & 31, by = blockIdx.x >> 5;
    const int rowBase = by * 128, colBase = bx * 128;
    const int wr = w >> 1, wc = w & 1;

    // per-block bandwidth (tiny redundant reduction; saves a kernel launch)
    if (tid < 64) {
        float s = 0.f;
        for (int k = tid; k < D; k += 64) { float v = colsum[k]; s += v * v; }
        #pragma unroll
        for (int m = 32; m; m >>= 1) s += __shfl_xor(s, m);
        if (tid == 0) {
            double total = 2.0 * (double)N * (double)(*sumsq) - 2.0 * (double)s;
            bwS = (float)(total / ((double)N * (double)N - (double)N) * 0.25);
        }
    }

    f32x4 zero = {0.f, 0.f, 0.f, 0.f};
    f32x4 acc[4][4];
    #pragma unroll
    for (int i = 0; i < 4; i++)
        #pragma unroll
        for (int j = 0; j < 4; j++) acc[i][j] = zero;

    // staging: slot f = q*256 + tid; row = f&127, kgroup = f>>7
    const int fr = tid & 127;
    const int g0 = tid >> 7;  // 0/1 for q=0; q=1 is kgroup+2 => +16 elements
    const u16* gA0 = hi + (size_t)(rowBase + fr) * D + g0 * 8;
    const u16* gB0 = hi + (size_t)(colBase + fr) * D + g0 * 8;
    u16* lA0 = As + (size_t)(w * 64) * 8;
    u16* lA1 = As + (size_t)(256 + w * 64) * 8;
    u16* lB0 = Bs + (size_t)(w * 64) * 8;
    u16* lB1 = Bs + (size_t)(256 + w * 64) * 8;

    // fragment read slot bases: slot = (l>>4)*128 + (quad*64 + m*16 + (l&15))
    const int arow = (l >> 4) * 128 + wr * 64 + (l & 15);
    const int brow = (l >> 4) * 128 + wc * 64 + (l & 15);

    for (int k0 = 0; k0 < D; k0 += 32) {
        __syncthreads();  // previous tile's ds_reads complete
        gll16(gA0 + k0,      lA0);
        gll16(gA0 + k0 + 16, lA1);
        gll16(gB0 + k0,      lB0);
        gll16(gB0 + k0 + 16, lB1);
        __syncthreads();  // vmcnt drained before barrier -> LDS ready
        bf16x8 af[4], bf[4];
        #pragma unroll
        for (int m = 0; m < 4; m++) af[m] = *(const bf16x8*)(As + (size_t)(arow + m * 16) * 8);
        #pragma unroll
        for (int n = 0; n < 4; n++) bf[n] = *(const bf16x8*)(Bs + (size_t)(brow + n * 16) * 8);
        #pragma unroll
        for (int m = 0; m < 4; m++)
            #pragma unroll
            for (int n = 0; n < 4; n++)
                acc[m][n] = __builtin_amdgcn_mfma_f32_16x16x32_bf16(af[m], bf[n], acc[m][n], 0, 0, 0);
    }

    // ---- epilogue: L2 -> sum of 5 RBF kernels via u^{1,2,4,8,16} -> row stats ----
    const float bw = bwS;
    const float c4 = 1.0f / (16.0f * bw);      // smallest inverse bandwidth
    constexpr float INV_T = 1.0f / 0.35f;      // 1/(TEMPERATURE*KERNEL_NUM)

    const int col0 = colBase + wc * 64 + (l & 15);
    float sqC[4]; int labC[4];
    #pragma unroll
    for (int n = 0; n < 4; n++) { sqC[n] = sqh[col0 + n * 16]; labC[n] = lab[col0 + n * 16]; }
    const int rbase = rowBase + wr * 64 + (l >> 4) * 4;
    float* dOut = denomP + (size_t)(bx * 2 + wc) * N;
    float* sOut = SP + (size_t)(bx * 2 + wc) * N;

    #pragma unroll
    for (int m = 0; m < 4; m++) {
        #pragma unroll
        for (int rg = 0; rg < 4; rg++) {
            const int r = rbase + m * 16 + rg;
            const float sqR = sqh[r];
            const int labR = lab[r];
            float dA = 0.f, sA = 0.f;
            #pragma unroll
            for (int n = 0; n < 4; n++) {
                float gv = acc[m][n][rg];
                float L2 = fmaxf(sqR + sqC[n] - 2.0f * gv, 0.0f);
                float u = __expf(-L2 * c4);
                float u2 = u * u, u4 = u2 * u2, u8 = u4 * u4, u16v = u8 * u8;
                float k5 = ((((u + u2) + u4) + u8) + u16v) - 5.0f;  // kern - 5 (diag -> 0)
                dA += __expf(k5 * INV_T);   // diag contributes ~1.0, subtracted in finalize
                if (labR == labC[n]) sA += k5;
            }
            #pragma unroll
            for (int mm = 1; mm <= 8; mm <<= 1) {
                dA += __shfl_xor(dA, mm);
                sA += __shfl_xor(sA, mm);
            }
            if ((l & 15) == 0) {
                dOut[r] = dA;
                sOut[r] = sA * INV_T;
            }
        }
    }
}

// ============ finalize: combine 64 column-slab partials ============
__global__ __launch_bounds__(1024) void finalize2_kernel(const float* __restrict__ denomP,
                                                         const float* __restrict__ SP,
                                                         const int* __restrict__ lab,
                                                         const int* __restrict__ cnt,
                                                         float* __restrict__ out) {
    const int tid = threadIdx.x;
    float lsum = 0.f, vcnt = 0.f;
    for (int r = tid; r < N; r += 1024) {
        float dsum = -1.0f;  // exact diagonal exp-term removal
        float ssum = 0.f;
        for (int b = 0; b < 64; b++) {
            dsum += denomP[(size_t)b * N + r];
            ssum += SP[(size_t)b * N + r];
        }
        int P = cnt[lab[r]] - 1;
        if (P > 0) {
            float fl = (float)P;
            lsum -= (ssum - fl * logf(dsum)) / fl;
            vcnt += 1.f;
        }
    }
    __shared__ float s1[16], s2[16];
    int lane = tid & 63, wv = tid >> 6;
    #pragma unroll
    for (int m = 32; m; m >>= 1) {
        lsum += __shfl_xor(lsum, m);
        vcnt += __shfl_xor(vcnt, m);
    }
    if (lane == 0) { s1[wv] = lsum; s2[wv] = vcnt; }
    __syncthreads();
    if (wv == 0) {
        float a = (lane < 16) ? s1[lane] : 0.f;
        float b = (lane < 16) ? s2[lane] : 0.f;
        #pragma unroll
        for (int m = 8; m; m >>= 1) {
            a += __shfl_xor(a, m);
            b += __shfl_xor(b, m);
        }
        if (lane == 0) out[0] = a / fmaxf(b, 1.0f);
    }
}

// ======================================================================
// ================= fallback fp32 path (round-1, known-good) ===========
// ======================================================================
constexpr int WS_FLOATS_OLD = 12802 + 32;

__global__ __launch_bounds__(256) void rowsq_kernel(const float* __restrict__ X,
                                                    float* __restrict__ sq,
                                                    float* __restrict__ sumsq) {
    int wave = threadIdx.x >> 6;
    int lane = threadIdx.x & 63;
    int row = blockIdx.x * 4 + wave;
    const float4* p = (const float4*)(X + (size_t)row * D);
    float4 v0 = p[lane * 2];
    float4 v1 = p[lane * 2 + 1];
    float s = v0.x * v0.x + v0.y * v0.y + v0.z * v0.z + v0.w * v0.w
            + v1.x * v1.x + v1.y * v1.y + v1.z * v1.z + v1.w * v1.w;
    #pragma unroll
    for (int m = 32; m; m >>= 1) s += __shfl_xor(s, m);
    if (lane == 0) { sq[row] = s; atomicAdd(sumsq, s); }
}

__global__ __launch_bounds__(256) void colsum_kernel(const float* __restrict__ X,
                                                     float* __restrict__ colsum) {
    int c0 = threadIdx.x;
    int c1 = threadIdx.x + 256;
    int r0 = blockIdx.x * 64;
    float s0 = 0.f, s1 = 0.f;
    for (int r = r0; r < r0 + 64; r++) {
        s0 += X[(size_t)r * D + c0];
        s1 += X[(size_t)r * D + c1];
    }
    atomicAdd(&colsum[c0], s0);
    atomicAdd(&colsum[c1], s1);
}

__global__ __launch_bounds__(256) void hist_kernel(const int* __restrict__ lab,
                                                   int* __restrict__ cnt) {
    int i = blockIdx.x * 256 + threadIdx.x;
    if (i < N) atomicAdd(&cnt[lab[i]], 1);
}

__global__ __launch_bounds__(64) void bw_kernel(const float* __restrict__ colsum,
                                                const float* __restrict__ sumsq,
                                                float* __restrict__ bw) {
    int lane = threadIdx.x;
    float s = 0.f;
    for (int k = lane; k < D; k += 64) { float v = colsum[k]; s += v * v; }
    #pragma unroll
    for (int m = 32; m; m >>= 1) s += __shfl_xor(s, m);
    if (lane == 0) {
        double total = 2.0 * (double)N * (double)(*sumsq) - 2.0 * (double)s;
        double b = total / ((double)N * (double)N - (double)N);
        *bw = (float)(b / 4.0);
    }
}

constexpr int BM = 128, BN = 128, BK = 16;

__global__ __launch_bounds__(256) void gemm_fused_kernel(const float* __restrict__ X,
                                                         const int* __restrict__ lab,
                                                         const float* __restrict__ sq,
                                                         const float* __restrict__ bwp,
                                                         float* __restrict__ denom,
                                                         float* __restrict__ Ssum) {
    __shared__ float As[BK][BM];
    __shared__ float Bs[BK][BN];
    const int tid = threadIdx.x;
    const int nbx = N / BN;
    const int bx = blockIdx.x % nbx;
    const int by = blockIdx.x / nbx;
    const int rowBase = by * BM, colBase = bx * BN;
    const int lr = tid >> 1;
    const int lc = (tid & 1) * 8;
    const float* Ap = X + (size_t)(rowBase + lr) * D + lc;
    const float* Bp = X + (size_t)(colBase + lr) * D + lc;
    const int ty = tid >> 4, tx = tid & 15;

    float acc[8][8];
    #pragma unroll
    for (int i = 0; i < 8; i++)
        #pragma unroll
        for (int j = 0; j < 8; j++) acc[i][j] = 0.f;

    for (int k0 = 0; k0 < D; k0 += BK) {
        float4 a0 = *(const float4*)(Ap + k0);
        float4 a1 = *(const float4*)(Ap + k0 + 4);
        float4 b0 = *(const float4*)(Bp + k0);
        float4 b1 = *(const float4*)(Bp + k0 + 4);
        __syncthreads();
        As[lc + 0][lr] = a0.x; As[lc + 1][lr] = a0.y;
        As[lc + 2][lr] = a0.z; As[lc + 3][lr] = a0.w;
        As[lc + 4][lr] = a1.x; As[lc + 5][lr] = a1.y;
        As[lc + 6][lr] = a1.z; As[lc + 7][lr] = a1.w;
        Bs[lc + 0][lr] = b0.x; Bs[lc + 1][lr] = b0.y;
        Bs[lc + 2][lr] = b0.z; Bs[lc + 3][lr] = b0.w;
        Bs[lc + 4][lr] = b1.x; Bs[lc + 5][lr] = b1.y;
        Bs[lc + 6][lr] = b1.z; Bs[lc + 7][lr] = b1.w;
        __syncthreads();
        #pragma unroll
        for (int kk = 0; kk < BK; kk++) {
            float a[8], b[8];
            *(float4*)&a[0] = *(const float4*)&As[kk][ty * 8];
            *(float4*)&a[4] = *(const float4*)&As[kk][ty * 8 + 4];
            *(float4*)&b[0] = *(const float4*)&Bs[kk][tx * 8];
            *(float4*)&b[4] = *(const float4*)&Bs[kk][tx * 8 + 4];
            #pragma unroll
            for (int i = 0; i < 8; i++)
                #pragma unroll
                for (int j = 0; j < 8; j++)
                    acc[i][j] = fmaf(a[i], b[j], acc[i][j]);
        }
    }

    const float bw = *bwp;
    const float inv0 = 1.0f / bw;
    const float invb[5] = {inv0, inv0 * 0.5f, inv0 * 0.25f, inv0 * 0.125f, inv0 * 0.0625f};
    constexpr float INV_T = 1.0f / 0.35f;

    float sqR[8], sqC[8];
    int labR[8], labC[8];
    #pragma unroll
    for (int i = 0; i < 8; i++) {
        int r = rowBase + ty * 8 + i;
        sqR[i] = sq[r]; labR[i] = lab[r];
    }
    #pragma unroll
    for (int j = 0; j < 8; j++) {
        int c = colBase + tx * 8 + j;
        sqC[j] = sq[c]; labC[j] = lab[c];
    }

    #pragma unroll
    for (int i = 0; i < 8; i++) {
        int r = rowBase + ty * 8 + i;
        float dAcc = 0.f, sAcc = 0.f;
        #pragma unroll
        for (int j = 0; j < 8; j++) {
            int c = colBase + tx * 8 + j;
            float L2 = fmaxf(sqR[i] + sqC[j] - 2.0f * acc[i][j], 0.0f);
            float kern = 0.f;
            #pragma unroll
            for (int m = 0; m < 5; m++) kern += __expf(-L2 * invb[m]);
            float logit = (kern - 5.0f) * INV_T;
            if (r != c) {
                dAcc += __expf(logit);
                if (labR[i] == labC[j]) sAcc += logit;
            }
        }
        #pragma unroll
        for (int m = 8; m; m >>= 1) {
            dAcc += __shfl_xor(dAcc, m);
            sAcc += __shfl_xor(sAcc, m);
        }
        if (tx == 0) {
            atomicAdd(&denom[r], dAcc);
            atomicAdd(&Ssum[r], sAcc);
        }
    }
}

__global__ __launch_bounds__(1024) void finalize_kernel(const float* __restrict__ denom,
                                                        const float* __restrict__ Ssum,
                                                        const int* __restrict__ lab,
                                                        const int* __restrict__ cnt,
                                                        float* __restrict__ out) {
    int tid = threadIdx.x;
    float lsum = 0.f, vcnt = 0.f;
    for (int r = tid; r < N; r += 1024) {
        int P = cnt[lab[r]] - 1;
        if (P > 0) {
            float fl = (float)P;
            float mean = (Ssum[r] - fl * logf(denom[r])) / fl;
            lsum -= mean;
            vcnt += 1.f;
        }
    }
    __shared__ float s1[16], s2[16];
    int lane = tid & 63, wv = tid >> 6;
    #pragma unroll
    for (int m = 32; m; m >>= 1) {
        lsum += __shfl_xor(lsum, m);
        vcnt += __shfl_xor(vcnt, m);
    }
    if (lane == 0) { s1[wv] = lsum; s2[wv] = vcnt; }
    __syncthreads();
    if (wv == 0) {
        float a = (lane < 16) ? s1[lane] : 0.f;
        float b = (lane < 16) ? s2[lane] : 0.f;
        #pragma unroll
        for (int m = 8; m; m >>= 1) {
            a += __shfl_xor(a, m);
            b += __shfl_xor(b, m);
        }
        if (lane == 0) out[0] = a / fmaxf(b, 1.0f);
    }
}

extern "C" void kernel_launch(void* const* d_in, const int* in_sizes, int n_in,
                              void* d_out, int out_size, void* d_ws, size_t ws_size,
                              hipStream_t stream) {
    const float* X = (const float*)d_in[0];
    const int* lab = (const int*)d_in[1];
    float* ws = (float*)d_ws;

    if (ws_size >= WS_NEED) {
        u16* hi = (u16*)ws;
        float* sqh = ws + OFF_SQH;
        float* denomP = ws + OFF_DENOMP;
        float* SP = ws + OFF_SP;
        float* colsum = ws + OFF_COLSUM;
        float* sumsq = ws + OFF_SUMSQ;
        int* cnt = (int*)(ws + OFF_CNT);

        hipMemsetAsync(colsum, 0, (D + 1 + NCLASS) * sizeof(float), stream);
        prep_kernel<<<N / 64, 256, 0, stream>>>(X, lab, hi, sqh, colsum, sumsq, cnt);
        gemm_mfma_kernel<<<(N / 128) * (N / 128), 256, 0, stream>>>(hi, lab, sqh, colsum,
                                                                    sumsq, denomP, SP);
        finalize2_kernel<<<1, 1024, 0, stream>>>(denomP, SP, lab, cnt, (float*)d_out);
    } else {
        float* sq = ws;
        float* denom = ws + 4096;
        float* Ssum = ws + 8192;
        float* colsum = ws + 12288;
        float* sumsq = ws + 12800;
        float* bw = ws + 12801;
        int* cnt = (int*)(ws + 12802);

        hipMemsetAsync(d_ws, 0, WS_FLOATS_OLD * sizeof(float), stream);
        rowsq_kernel<<<N / 4, 256, 0, stream>>>(X, sq, sumsq);
        colsum_kernel<<<N / 64, 256, 0, stream>>>(X, colsum);
        hist_kernel<<<(N + 255) / 256, 256, 0, stream>>>(lab, cnt);
        bw_kernel<<<1, 64, 0, stream>>>(colsum, sumsq, bw);
        gemm_fused_kernel<<<(N / BM) * (N / BN), 256, 0, stream>>>(X, lab, sq, bw, denom, Ssum);
        finalize_kernel<<<1, 1024, 0, stream>>>(denom, Ssum, lab, cnt, (float*)d_out);
    }
}

// Round 3
// 92.458 us; speedup vs baseline: 3.2761x; 1.2379x over previous
//
#include <hip/hip_runtime.h>
#include <math.h>

#define N 4096
#define D 512
#define NCLASS 31

typedef unsigned short u16;
typedef unsigned int u32;
typedef short bf16x8 __attribute__((ext_vector_type(8)));
typedef float f32x4 __attribute__((ext_vector_type(4)));

__device__ __forceinline__ u32 f2bf(float x) {
    u32 u = __float_as_uint(x);
    return (u + 0x7FFFu + ((u >> 16) & 1u)) >> 16;  // RNE bf16 (no inf/nan in data)
}
__device__ __forceinline__ float bf2f(u32 h) {
    return __uint_as_float(h << 16);
}

__device__ __forceinline__ void gll16(const void* g, void* l) {
    __builtin_amdgcn_global_load_lds(
        (const __attribute__((address_space(1))) u32*)g,
        (__attribute__((address_space(3))) u32*)l, 16, 0, 0);
}

// ---------------- ws layout (float units) ----------------
constexpr size_t HI_FLOATS  = (size_t)N * D / 2;   // bf16 copy of X
constexpr size_t OFF_SQH    = HI_FLOATS;           // N row sq-norms
constexpr size_t OFF_DEN    = OFF_SQH + N;         // N denom accumulators
constexpr size_t OFF_S      = OFF_DEN + N;         // N S accumulators
constexpr size_t OFF_COLSUM = OFF_S + N;           // D
constexpr size_t OFF_SUMSQ  = OFF_COLSUM + D;      // 1
constexpr size_t OFF_CNT    = OFF_SUMSQ + 1;       // NCLASS ints
constexpr size_t ZERO_OFF    = OFF_DEN;
constexpr size_t ZERO_FLOATS = N + N + D + 1 + NCLASS + 8;
constexpr size_t WS_NEED     = (OFF_CNT + NCLASS + 8) * 4;

// ============ prep: fp32->bf16 + colsum + sumsq + rowsq + hist ============
__global__ __launch_bounds__(256) void prep_kernel(const float* __restrict__ X,
                                                   const int* __restrict__ lab,
                                                   u16* __restrict__ hi,
                                                   float* __restrict__ sqh,
                                                   float* __restrict__ colsum,
                                                   float* __restrict__ sumsq,
                                                   int* __restrict__ cnt) {
    const int t = threadIdx.x;
    const int r0 = blockIdx.x * 16;
    float cs0 = 0.f, cs1 = 0.f, ss = 0.f;
    #pragma unroll 4
    for (int r = r0; r < r0 + 16; r++) {
        float2 v = *(const float2*)(X + (size_t)r * D + t * 2);
        u32 h0 = f2bf(v.x), h1 = f2bf(v.y);
        *(u32*)(hi + (size_t)r * D + t * 2) = h0 | (h1 << 16);
        float q0 = bf2f(h0), q1 = bf2f(h1);
        cs0 += q0; cs1 += q1;
        ss += q0 * q0 + q1 * q1;
    }
    atomicAdd(&colsum[t * 2], cs0);
    atomicAdd(&colsum[t * 2 + 1], cs1);
    __shared__ float red[4];
    const int ln = t & 63, wv = t >> 6;
    #pragma unroll
    for (int m = 32; m; m >>= 1) ss += __shfl_xor(ss, m);
    if (ln == 0) red[wv] = ss;
    if (t < 16) atomicAdd(&cnt[lab[r0 + t]], 1);
    __syncthreads();
    if (t == 0) atomicAdd(sumsq, red[0] + red[1] + red[2] + red[3]);
    // per-row sq-norm from hi (written by this block, visible post-barrier)
    #pragma unroll
    for (int i = 0; i < 4; i++) {
        int r = r0 + wv * 4 + i;
        bf16x8 v = *(const bf16x8*)(hi + (size_t)r * D + ln * 8);
        float s = 0.f;
        #pragma unroll
        for (int j = 0; j < 8; j++) { float f = bf2f((u16)v[j]); s += f * f; }
        #pragma unroll
        for (int m = 32; m; m >>= 1) s += __shfl_xor(s, m);
        if (ln == 0) sqh[r] = s;
    }
}

// ============ symmetric fused MFMA Gram + RBF + contrastive stats ============
// Upper-triangle blocks only (528). 128x128 tile, 4 waves (2x2 quadrants),
// 16x16x32 bf16 MFMA, BK=32, double-buffered LDS, 1 barrier per K-step.
// Off-diagonal blocks emit BOTH row-side and col-side stats (kern symmetric).
__global__ __launch_bounds__(256) void gemm_mfma_kernel(const u16* __restrict__ hi,
                                                        const int* __restrict__ lab,
                                                        const float* __restrict__ sqh,
                                                        const float* __restrict__ colsum,
                                                        const float* __restrict__ sumsq,
                                                        float* __restrict__ denom,
                                                        float* __restrict__ Ssum) {
    __shared__ u16 As[2][128 * 32];
    __shared__ u16 Bs[2][128 * 32];
    __shared__ float bwS;
    const int tid = threadIdx.x;
    const int w = tid >> 6, l = tid & 63;

    // triangular block decode: by <= bx
    int b = blockIdx.x, by = 0;
    while (b >= 32 - by) { b -= 32 - by; ++by; }
    const int bx = by + b;
    const bool offdiag = (bx != by);
    const int rowBase = by * 128, colBase = bx * 128;
    const int wr = w >> 1, wc = w & 1;

    // per-block bandwidth (redundant tiny reduction; saves a launch)
    if (tid < 64) {
        float s = 0.f;
        for (int k = tid; k < D; k += 64) { float v = colsum[k]; s += v * v; }
        #pragma unroll
        for (int m = 32; m; m >>= 1) s += __shfl_xor(s, m);
        if (tid == 0) {
            double total = 2.0 * (double)N * (double)(*sumsq) - 2.0 * (double)s;
            bwS = (float)(total / ((double)N * (double)N - (double)N) * 0.25);
        }
    }

    f32x4 zero = {0.f, 0.f, 0.f, 0.f};
    f32x4 acc[4][4];
    #pragma unroll
    for (int i = 0; i < 4; i++)
        #pragma unroll
        for (int j = 0; j < 4; j++) acc[i][j] = zero;

    // staging: slot s (16B) = row (s&127), kgroup (s>>7); linear lane->slot
    const int fr = tid & 127;
    const int g0 = tid >> 7;
    const u16* gA0 = hi + (size_t)(rowBase + fr) * D + g0 * 8;
    const u16* gB0 = hi + (size_t)(colBase + fr) * D + g0 * 8;
    // fragment read slot: (l>>4)*128 + quad*64 + m*16 + (l&15)
    const int arow = (l >> 4) * 128 + wr * 64 + (l & 15);
    const int brow = (l >> 4) * 128 + wc * 64 + (l & 15);

    auto stage = [&](int buf, int k0) {
        gll16(gA0 + k0,      &As[buf][(size_t)(w * 64) * 8]);
        gll16(gA0 + k0 + 16, &As[buf][(size_t)(256 + w * 64) * 8]);
        gll16(gB0 + k0,      &Bs[buf][(size_t)(w * 64) * 8]);
        gll16(gB0 + k0 + 16, &Bs[buf][(size_t)(256 + w * 64) * 8]);
    };

    stage(0, 0);
    #pragma unroll 2
    for (int t = 0; t < 16; ++t) {
        __syncthreads();  // drains prefetch vmcnt + prior ds_reads, all waves
        if (t < 15) stage((t & 1) ^ 1, (t + 1) * 32);
        const u16* Ab = As[t & 1];
        const u16* Bb = Bs[t & 1];
        bf16x8 af[4], bf[4];
        #pragma unroll
        for (int m = 0; m < 4; m++) af[m] = *(const bf16x8*)(Ab + (size_t)(arow + m * 16) * 8);
        #pragma unroll
        for (int n = 0; n < 4; n++) bf[n] = *(const bf16x8*)(Bb + (size_t)(brow + n * 16) * 8);
        #pragma unroll
        for (int m = 0; m < 4; m++)
            #pragma unroll
            for (int n = 0; n < 4; n++)
                acc[m][n] = __builtin_amdgcn_mfma_f32_16x16x32_bf16(af[m], bf[n], acc[m][n], 0, 0, 0);
    }

    // ---- epilogue: L2 -> 5-kernel sum via u^{1,2,4,8,16} -> row+col stats ----
    const float bw = bwS;
    const float c4 = 1.0f / (16.0f * bw);
    constexpr float INV_T = 1.0f / 0.35f;  // 1/(TEMPERATURE*KERNEL_NUM)

    const int col0 = colBase + wc * 64 + (l & 15);
    float sqC[4]; int labC[4];
    #pragma unroll
    for (int n = 0; n < 4; n++) { sqC[n] = sqh[col0 + n * 16]; labC[n] = lab[col0 + n * 16]; }
    const int rbase = rowBase + wr * 64 + (l >> 4) * 4;

    float dCol[4] = {0.f, 0.f, 0.f, 0.f};
    float sCol[4] = {0.f, 0.f, 0.f, 0.f};

    #pragma unroll
    for (int m = 0; m < 4; m++) {
        #pragma unroll
        for (int rg = 0; rg < 4; rg++) {
            const int r = rbase + m * 16 + rg;
            const float sqR = sqh[r];
            const int labR = lab[r];
            float dA = 0.f, sA = 0.f;
            #pragma unroll
            for (int n = 0; n < 4; n++) {
                float gv = acc[m][n][rg];
                float L2 = fmaxf(sqR + sqC[n] - 2.0f * gv, 0.0f);
                float u = __expf(-L2 * c4);
                float u2 = u * u, u4 = u2 * u2, u8 = u4 * u4, u16v = u8 * u8;
                float k5 = ((((u + u2) + u4) + u8) + u16v) - 5.0f;  // kern-5 (diag->~0)
                float e = __expf(k5 * INV_T);
                dA += e;
                dCol[n] += e;
                if (labR == labC[n]) { sA += k5; sCol[n] += k5; }
            }
            #pragma unroll
            for (int mm = 1; mm <= 8; mm <<= 1) {
                dA += __shfl_xor(dA, mm);
                sA += __shfl_xor(sA, mm);
            }
            if ((l & 15) == 0) {
                atomicAdd(&denom[r], dA);
                atomicAdd(&Ssum[r], sA * INV_T);
            }
        }
    }
    if (offdiag) {  // transposed contributions: reduce over the row axis
        #pragma unroll
        for (int n = 0; n < 4; n++) {
            float d = dCol[n], s = sCol[n];
            d += __shfl_xor(d, 16); d += __shfl_xor(d, 32);
            s += __shfl_xor(s, 16); s += __shfl_xor(s, 32);
            if (l < 16) {
                atomicAdd(&denom[col0 + n * 16], d);
                atomicAdd(&Ssum[col0 + n * 16], s * INV_T);
            }
        }
    }
}

// ============ finalize ============
__global__ __launch_bounds__(1024) void finalize_kernel(const float* __restrict__ denom,
                                                        const float* __restrict__ Ssum,
                                                        const int* __restrict__ lab,
                                                        const int* __restrict__ cnt,
                                                        float* __restrict__ out) {
    const int tid = threadIdx.x;
    float lsum = 0.f, vcnt = 0.f;
    for (int r = tid; r < N; r += 1024) {
        float dsum = denom[r] - 1.0f;  // exact diagonal exp-term removal
        int P = cnt[lab[r]] - 1;
        if (P > 0) {
            float fl = (float)P;
            lsum -= (Ssum[r] - fl * logf(dsum)) / fl;
            vcnt += 1.f;
        }
    }
    __shared__ float s1[16], s2[16];
    int lane = tid & 63, wv = tid >> 6;
    #pragma unroll
    for (int m = 32; m; m >>= 1) {
        lsum += __shfl_xor(lsum, m);
        vcnt += __shfl_xor(vcnt, m);
    }
    if (lane == 0) { s1[wv] = lsum; s2[wv] = vcnt; }
    __syncthreads();
    if (wv == 0) {
        float a = (lane < 16) ? s1[lane] : 0.f;
        float b = (lane < 16) ? s2[lane] : 0.f;
        #pragma unroll
        for (int m = 8; m; m >>= 1) {
            a += __shfl_xor(a, m);
            b += __shfl_xor(b, m);
        }
        if (lane == 0) out[0] = a / fmaxf(b, 1.0f);
    }
}

// ======================================================================
// ================= fallback fp32 path (round-1, known-good) ===========
// ======================================================================
constexpr int WS_FLOATS_OLD = 12802 + 32;

__global__ __launch_bounds__(256) void rowsq_kernel(const float* __restrict__ X,
                                                    float* __restrict__ sq,
                                                    float* __restrict__ sumsq) {
    int wave = threadIdx.x >> 6;
    int lane = threadIdx.x & 63;
    int row = blockIdx.x * 4 + wave;
    const float4* p = (const float4*)(X + (size_t)row * D);
    float4 v0 = p[lane * 2];
    float4 v1 = p[lane * 2 + 1];
    float s = v0.x * v0.x + v0.y * v0.y + v0.z * v0.z + v0.w * v0.w
            + v1.x * v1.x + v1.y * v1.y + v1.z * v1.z + v1.w * v1.w;
    #pragma unroll
    for (int m = 32; m; m >>= 1) s += __shfl_xor(s, m);
    if (lane == 0) { sq[row] = s; atomicAdd(sumsq, s); }
}

__global__ __launch_bounds__(256) void colsum_kernel(const float* __restrict__ X,
                                                     float* __restrict__ colsum) {
    int c0 = threadIdx.x;
    int c1 = threadIdx.x + 256;
    int r0 = blockIdx.x * 64;
    float s0 = 0.f, s1 = 0.f;
    for (int r = r0; r < r0 + 64; r++) {
        s0 += X[(size_t)r * D + c0];
        s1 += X[(size_t)r * D + c1];
    }
    atomicAdd(&colsum[c0], s0);
    atomicAdd(&colsum[c1], s1);
}

__global__ __launch_bounds__(256) void hist_kernel(const int* __restrict__ lab,
                                                   int* __restrict__ cnt) {
    int i = blockIdx.x * 256 + threadIdx.x;
    if (i < N) atomicAdd(&cnt[lab[i]], 1);
}

__global__ __launch_bounds__(64) void bw_kernel(const float* __restrict__ colsum,
                                                const float* __restrict__ sumsq,
                                                float* __restrict__ bw) {
    int lane = threadIdx.x;
    float s = 0.f;
    for (int k = lane; k < D; k += 64) { float v = colsum[k]; s += v * v; }
    #pragma unroll
    for (int m = 32; m; m >>= 1) s += __shfl_xor(s, m);
    if (lane == 0) {
        double total = 2.0 * (double)N * (double)(*sumsq) - 2.0 * (double)s;
        double b = total / ((double)N * (double)N - (double)N);
        *bw = (float)(b / 4.0);
    }
}

constexpr int BM = 128, BN = 128, BK = 16;

__global__ __launch_bounds__(256) void gemm_fused_kernel(const float* __restrict__ X,
                                                         const int* __restrict__ lab,
                                                         const float* __restrict__ sq,
                                                         const float* __restrict__ bwp,
                                                         float* __restrict__ denom,
                                                         float* __restrict__ Ssum) {
    __shared__ float As[BK][BM];
    __shared__ float Bs[BK][BN];
    const int tid = threadIdx.x;
    const int nbx = N / BN;
    const int bx = blockIdx.x % nbx;
    const int by = blockIdx.x / nbx;
    const int rowBase = by * BM, colBase = bx * BN;
    const int lr = tid >> 1;
    const int lc = (tid & 1) * 8;
    const float* Ap = X + (size_t)(rowBase + lr) * D + lc;
    const float* Bp = X + (size_t)(colBase + lr) * D + lc;
    const int ty = tid >> 4, tx = tid & 15;

    float acc[8][8];
    #pragma unroll
    for (int i = 0; i < 8; i++)
        #pragma unroll
        for (int j = 0; j < 8; j++) acc[i][j] = 0.f;

    for (int k0 = 0; k0 < D; k0 += BK) {
        float4 a0 = *(const float4*)(Ap + k0);
        float4 a1 = *(const float4*)(Ap + k0 + 4);
        float4 b0 = *(const float4*)(Bp + k0);
        float4 b1 = *(const float4*)(Bp + k0 + 4);
        __syncthreads();
        As[lc + 0][lr] = a0.x; As[lc + 1][lr] = a0.y;
        As[lc + 2][lr] = a0.z; As[lc + 3][lr] = a0.w;
        As[lc + 4][lr] = a1.x; As[lc + 5][lr] = a1.y;
        As[lc + 6][lr] = a1.z; As[lc + 7][lr] = a1.w;
        Bs[lc + 0][lr] = b0.x; Bs[lc + 1][lr] = b0.y;
        Bs[lc + 2][lr] = b0.z; Bs[lc + 3][lr] = b0.w;
        Bs[lc + 4][lr] = b1.x; Bs[lc + 5][lr] = b1.y;
        Bs[lc + 6][lr] = b1.z; Bs[lc + 7][lr] = b1.w;
        __syncthreads();
        #pragma unroll
        for (int kk = 0; kk < BK; kk++) {
            float a[8], b[8];
            *(float4*)&a[0] = *(const float4*)&As[kk][ty * 8];
            *(float4*)&a[4] = *(const float4*)&As[kk][ty * 8 + 4];
            *(float4*)&b[0] = *(const float4*)&Bs[kk][tx * 8];
            *(float4*)&b[4] = *(const float4*)&Bs[kk][tx * 8 + 4];
            #pragma unroll
            for (int i = 0; i < 8; i++)
                #pragma unroll
                for (int j = 0; j < 8; j++)
                    acc[i][j] = fmaf(a[i], b[j], acc[i][j]);
        }
    }

    const float bw = *bwp;
    const float inv0 = 1.0f / bw;
    const float invb[5] = {inv0, inv0 * 0.5f, inv0 * 0.25f, inv0 * 0.125f, inv0 * 0.0625f};
    constexpr float INV_T = 1.0f / 0.35f;

    float sqR[8], sqC[8];
    int labR[8], labC[8];
    #pragma unroll
    for (int i = 0; i < 8; i++) {
        int r = rowBase + ty * 8 + i;
        sqR[i] = sq[r]; labR[i] = lab[r];
    }
    #pragma unroll
    for (int j = 0; j < 8; j++) {
        int c = colBase + tx * 8 + j;
        sqC[j] = sq[c]; labC[j] = lab[c];
    }

    #pragma unroll
    for (int i = 0; i < 8; i++) {
        int r = rowBase + ty * 8 + i;
        float dAcc = 0.f, sAcc = 0.f;
        #pragma unroll
        for (int j = 0; j < 8; j++) {
            int c = colBase + tx * 8 + j;
            float L2 = fmaxf(sqR[i] + sqC[j] - 2.0f * acc[i][j], 0.0f);
            float kern = 0.f;
            #pragma unroll
            for (int m = 0; m < 5; m++) kern += __expf(-L2 * invb[m]);
            float logit = (kern - 5.0f) * INV_T;
            if (r != c) {
                dAcc += __expf(logit);
                if (labR[i] == labC[j]) sAcc += logit;
            }
        }
        #pragma unroll
        for (int m = 8; m; m >>= 1) {
            dAcc += __shfl_xor(dAcc, m);
            sAcc += __shfl_xor(sAcc, m);
        }
        if (tx == 0) {
            atomicAdd(&denom[r], dAcc);
            atomicAdd(&Ssum[r], sAcc);
        }
    }
}

__global__ __launch_bounds__(1024) void finalize_old_kernel(const float* __restrict__ denom,
                                                            const float* __restrict__ Ssum,
                                                            const int* __restrict__ lab,
                                                            const int* __restrict__ cnt,
                                                            float* __restrict__ out) {
    int tid = threadIdx.x;
    float lsum = 0.f, vcnt = 0.f;
    for (int r = tid; r < N; r += 1024) {
        int P = cnt[lab[r]] - 1;
        if (P > 0) {
            float fl = (float)P;
            float mean = (Ssum[r] - fl * logf(denom[r])) / fl;
            lsum -= mean;
            vcnt += 1.f;
        }
    }
    __shared__ float s1[16], s2[16];
    int lane = tid & 63, wv = tid >> 6;
    #pragma unroll
    for (int m = 32; m; m >>= 1) {
        lsum += __shfl_xor(lsum, m);
        vcnt += __shfl_xor(vcnt, m);
    }
    if (lane == 0) { s1[wv] = lsum; s2[wv] = vcnt; }
    __syncthreads();
    if (wv == 0) {
        float a = (lane < 16) ? s1[lane] : 0.f;
        float b = (lane < 16) ? s2[lane] : 0.f;
        #pragma unroll
        for (int m = 8; m; m >>= 1) {
            a += __shfl_xor(a, m);
            b += __shfl_xor(b, m);
        }
        if (lane == 0) out[0] = a / fmaxf(b, 1.0f);
    }
}

extern "C" void kernel_launch(void* const* d_in, const int* in_sizes, int n_in,
                              void* d_out, int out_size, void* d_ws, size_t ws_size,
                              hipStream_t stream) {
    const float* X = (const float*)d_in[0];
    const int* lab = (const int*)d_in[1];
    float* ws = (float*)d_ws;

    if (ws_size >= WS_NEED) {
        u16* hi = (u16*)ws;
        float* sqh = ws + OFF_SQH;
        float* denom = ws + OFF_DEN;
        float* S = ws + OFF_S;
        float* colsum = ws + OFF_COLSUM;
        float* sumsq = ws + OFF_SUMSQ;
        int* cnt = (int*)(ws + OFF_CNT);

        hipMemsetAsync(ws + ZERO_OFF, 0, ZERO_FLOATS * sizeof(float), stream);
        prep_kernel<<<N / 16, 256, 0, stream>>>(X, lab, hi, sqh, colsum, sumsq, cnt);
        gemm_mfma_kernel<<<(32 * 33) / 2, 256, 0, stream>>>(hi, lab, sqh, colsum,
                                                            sumsq, denom, S);
        finalize_kernel<<<1, 1024, 0, stream>>>(denom, S, lab, cnt, (float*)d_out);
    } else {
        float* sq = ws;
        float* denom = ws + 4096;
        float* Ssum = ws + 8192;
        float* colsum = ws + 12288;
        float* sumsq = ws + 12800;
        float* bw = ws + 12801;
        int* cnt = (int*)(ws + 12802);

        hipMemsetAsync(d_ws, 0, WS_FLOATS_OLD * sizeof(float), stream);
        rowsq_kernel<<<N / 4, 256, 0, stream>>>(X, sq, sumsq);
        colsum_kernel<<<N / 64, 256, 0, stream>>>(X, colsum);
        hist_kernel<<<(N + 255) / 256, 256, 0, stream>>>(lab, cnt);
        bw_kernel<<<1, 64, 0, stream>>>(colsum, sumsq, bw);
        gemm_fused_kernel<<<(N / BM) * (N / BN), 256, 0, stream>>>(X, lab, sq, bw, denom, Ssum);
        finalize_old_kernel<<<1, 1024, 0, stream>>>(denom, Ssum, lab, cnt, (float*)d_out);
    }
}

// Round 4
// 74.676 us; speedup vs baseline: 4.0561x; 1.2381x over previous
//
#include <hip/hip_runtime.h>
#include <math.h>

#define N 4096
#define D 512
#define NCLASS 31

typedef unsigned short u16;
typedef unsigned int u32;
typedef short bf16x8 __attribute__((ext_vector_type(8)));
typedef float f32x4 __attribute__((ext_vector_type(4)));

__device__ __forceinline__ u32 f2bf(float x) {
    u32 u = __float_as_uint(x);
    return (u + 0x7FFFu + ((u >> 16) & 1u)) >> 16;  // RNE bf16 (no inf/nan in data)
}
__device__ __forceinline__ float bf2f(u32 h) {
    return __uint_as_float(h << 16);
}

__device__ __forceinline__ void gll16(const void* g, void* l) {
    __builtin_amdgcn_global_load_lds(
        (const __attribute__((address_space(1))) u32*)g,
        (__attribute__((address_space(3))) u32*)l, 16, 0, 0);
}

// ---------------- ws layout (float units) ----------------
constexpr size_t HI_FLOATS  = (size_t)N * D / 2;   // bf16 copy of X
constexpr size_t OFF_SQH    = HI_FLOATS;           // N row sq-norms
constexpr size_t OFF_DEN    = OFF_SQH + N;         // N denom accumulators
constexpr size_t OFF_S      = OFF_DEN + N;         // N S accumulators
constexpr size_t OFF_COLSUM = OFF_S + N;           // D
constexpr size_t OFF_SUMSQ  = OFF_COLSUM + D;      // 1
constexpr size_t OFF_CNT    = OFF_SUMSQ + 1;       // NCLASS ints
constexpr size_t ZERO_OFF    = OFF_DEN;
constexpr size_t ZERO_FLOATS = N + N + D + 1 + NCLASS + 8;
constexpr size_t WS_NEED     = (OFF_CNT + NCLASS + 8) * 4;

// ============ prep: fp32->bf16 + colsum + sumsq + rowsq + hist ============
__global__ __launch_bounds__(256) void prep_kernel(const float* __restrict__ X,
                                                   const int* __restrict__ lab,
                                                   u16* __restrict__ hi,
                                                   float* __restrict__ sqh,
                                                   float* __restrict__ colsum,
                                                   float* __restrict__ sumsq,
                                                   int* __restrict__ cnt) {
    const int t = threadIdx.x;
    const int r0 = blockIdx.x * 16;
    float cs0 = 0.f, cs1 = 0.f, ss = 0.f;
    #pragma unroll 4
    for (int r = r0; r < r0 + 16; r++) {
        float2 v = *(const float2*)(X + (size_t)r * D + t * 2);
        u32 h0 = f2bf(v.x), h1 = f2bf(v.y);
        *(u32*)(hi + (size_t)r * D + t * 2) = h0 | (h1 << 16);
        float q0 = bf2f(h0), q1 = bf2f(h1);
        cs0 += q0; cs1 += q1;
        ss += q0 * q0 + q1 * q1;
    }
    atomicAdd(&colsum[t * 2], cs0);
    atomicAdd(&colsum[t * 2 + 1], cs1);
    __shared__ float red[4];
    const int ln = t & 63, wv = t >> 6;
    #pragma unroll
    for (int m = 32; m; m >>= 1) ss += __shfl_xor(ss, m);
    if (ln == 0) red[wv] = ss;
    if (t < 16) atomicAdd(&cnt[lab[r0 + t]], 1);
    __syncthreads();
    if (t == 0) atomicAdd(sumsq, red[0] + red[1] + red[2] + red[3]);
    // per-row sq-norm from hi (written by this block, visible post-barrier)
    #pragma unroll
    for (int i = 0; i < 4; i++) {
        int r = r0 + wv * 4 + i;
        bf16x8 v = *(const bf16x8*)(hi + (size_t)r * D + ln * 8);
        float s = 0.f;
        #pragma unroll
        for (int j = 0; j < 8; j++) { float f = bf2f((u16)v[j]); s += f * f; }
        #pragma unroll
        for (int m = 32; m; m >>= 1) s += __shfl_xor(s, m);
        if (ln == 0) sqh[r] = s;
    }
}

// ============ symmetric fused MFMA Gram + RBF + contrastive stats ============
// Upper-triangle 528 blocks. 128x128 tile, 4 waves (2x2 quadrants), 16x16x32
// bf16 MFMA, BK=32. Counted-vmcnt pipeline: 3 LDS buffers, prefetch depth 2,
// one raw s_barrier per K-step, NEVER vmcnt(0) in the loop (kills the
// vmcnt(0)-drain convoy that made rounds 2/3 latency-bound).
// Safety: a wave reaches step-t's barrier only after its step-(t-1) ds_reads
// completed (lgkmcnt precedes its MFMAs, in-order issue), so staging tile t+2
// into buf[(t-1)%3] after the barrier is race-free.
__global__ __launch_bounds__(256, 3) void gemm_mfma_kernel(const u16* __restrict__ hi,
                                                           const int* __restrict__ lab,
                                                           const float* __restrict__ sqh,
                                                           const float* __restrict__ colsum,
                                                           const float* __restrict__ sumsq,
                                                           float* __restrict__ denom,
                                                           float* __restrict__ Ssum) {
    __shared__ u16 As[3][128 * 32];
    __shared__ u16 Bs[3][128 * 32];
    __shared__ float bwS;
    const int tid = threadIdx.x;
    const int w = tid >> 6, l = tid & 63;

    // bijective XCD swizzle (528 = 8 * 66) then triangular decode (by <= bx)
    const int bid = blockIdx.x;
    int b = (bid & 7) * 66 + (bid >> 3);
    int by = 0;
    while (b >= 32 - by) { b -= 32 - by; ++by; }
    const int bx = by + b;
    const bool offdiag = (bx != by);
    const int rowBase = by * 128, colBase = bx * 128;
    const int wr = w >> 1, wc = w & 1;

    // bandwidth preamble (wave 0 only) BEFORE staging, so its loads drain
    // without perturbing the pipeline's counted vmcnt.
    if (tid < 64) {
        float s = 0.f;
        for (int k = tid; k < D; k += 64) { float v = colsum[k]; s += v * v; }
        #pragma unroll
        for (int m = 32; m; m >>= 1) s += __shfl_xor(s, m);
        if (tid == 0) {
            double total = 2.0 * (double)N * (double)(*sumsq) - 2.0 * (double)s;
            bwS = (float)(total / ((double)N * (double)N - (double)N) * 0.25);
        }
    }

    f32x4 zero = {0.f, 0.f, 0.f, 0.f};
    f32x4 acc[4][4];
    #pragma unroll
    for (int i = 0; i < 4; i++)
        #pragma unroll
        for (int j = 0; j < 4; j++) acc[i][j] = zero;

    // staging: slot s (16B) = row (s&127), kgroup (s>>7); linear lane->slot
    const int fr = tid & 127;
    const int g0 = tid >> 7;
    const u16* gA0 = hi + (size_t)(rowBase + fr) * D + g0 * 8;
    const u16* gB0 = hi + (size_t)(colBase + fr) * D + g0 * 8;
    // fragment read slot: (l>>4)*128 + quad*64 + m*16 + (l&15)
    const int arow = (l >> 4) * 128 + wr * 64 + (l & 15);
    const int brow = (l >> 4) * 128 + wc * 64 + (l & 15);

#define STAGE(BUF, K0) {                                      \
    gll16(gA0 + (K0),      &As[BUF][(size_t)(w * 64) * 8]);       \
    gll16(gA0 + (K0) + 16, &As[BUF][(size_t)(256 + w * 64) * 8]); \
    gll16(gB0 + (K0),      &Bs[BUF][(size_t)(w * 64) * 8]);       \
    gll16(gB0 + (K0) + 16, &Bs[BUF][(size_t)(256 + w * 64) * 8]); }

    STAGE(0, 0)
    STAGE(1, 32)

#define KSTEP(T, CNT) {                                                        \
    asm volatile("s_waitcnt vmcnt(" CNT ")\n\ts_barrier" ::: "memory");        \
    const u16* Ab = As[(T) % 3];                                               \
    const u16* Bb = Bs[(T) % 3];                                               \
    bf16x8 af[4], bfr[4];                                                      \
    _Pragma("unroll")                                                          \
    for (int m = 0; m < 4; m++) af[m] = *(const bf16x8*)(Ab + (size_t)(arow + m * 16) * 8); \
    _Pragma("unroll")                                                          \
    for (int n = 0; n < 4; n++) bfr[n] = *(const bf16x8*)(Bb + (size_t)(brow + n * 16) * 8); \
    _Pragma("unroll")                                                          \
    for (int m = 0; m < 4; m++)                                                \
        _Pragma("unroll")                                                      \
        for (int n = 0; n < 4; n++)                                            \
            acc[m][n] = __builtin_amdgcn_mfma_f32_16x16x32_bf16(af[m], bfr[n], acc[m][n], 0, 0, 0); \
    if ((T) + 2 < 16) STAGE(((T) + 2) % 3, ((T) + 2) * 32) }

    KSTEP(0, "4")  KSTEP(1, "4")  KSTEP(2, "4")  KSTEP(3, "4")
    KSTEP(4, "4")  KSTEP(5, "4")  KSTEP(6, "4")  KSTEP(7, "4")
    KSTEP(8, "4")  KSTEP(9, "4")  KSTEP(10, "4") KSTEP(11, "4")
    KSTEP(12, "4") KSTEP(13, "4") KSTEP(14, "4") KSTEP(15, "0")

#undef KSTEP
#undef STAGE

    // ---- epilogue: L2 -> 5-kernel sum via u^{1,2,4,8,16} -> row+col stats ----
    // bwS: written by tid0 before it reached barrier 0 => visible to all waves.
    const float bw = bwS;
    const float c4 = 1.0f / (16.0f * bw);
    constexpr float INV_T = 1.0f / 0.35f;  // 1/(TEMPERATURE*KERNEL_NUM)

    const int col0 = colBase + wc * 64 + (l & 15);
    float sqC[4]; int labC[4];
    #pragma unroll
    for (int n = 0; n < 4; n++) { sqC[n] = sqh[col0 + n * 16]; labC[n] = lab[col0 + n * 16]; }
    const int rbase = rowBase + wr * 64 + (l >> 4) * 4;

    float dCol[4] = {0.f, 0.f, 0.f, 0.f};
    float sCol[4] = {0.f, 0.f, 0.f, 0.f};

    #pragma unroll
    for (int m = 0; m < 4; m++) {
        #pragma unroll
        for (int rg = 0; rg < 4; rg++) {
            const int r = rbase + m * 16 + rg;
            const float sqR = sqh[r];
            const int labR = lab[r];
            float dA = 0.f, sA = 0.f;
            #pragma unroll
            for (int n = 0; n < 4; n++) {
                float gv = acc[m][n][rg];
                float L2 = fmaxf(sqR + sqC[n] - 2.0f * gv, 0.0f);
                float u = __expf(-L2 * c4);
                float u2 = u * u, u4 = u2 * u2, u8 = u4 * u4, u16v = u8 * u8;
                float k5 = ((((u + u2) + u4) + u8) + u16v) - 5.0f;  // kern-5 (diag->~0)
                float e = __expf(k5 * INV_T);
                dA += e;
                dCol[n] += e;
                if (labR == labC[n]) { sA += k5; sCol[n] += k5; }
            }
            #pragma unroll
            for (int mm = 1; mm <= 8; mm <<= 1) {
                dA += __shfl_xor(dA, mm);
                sA += __shfl_xor(sA, mm);
            }
            if ((l & 15) == 0) {
                atomicAdd(&denom[r], dA);
                atomicAdd(&Ssum[r], sA * INV_T);
            }
        }
    }
    if (offdiag) {  // transposed contributions: reduce over the row axis
        #pragma unroll
        for (int n = 0; n < 4; n++) {
            float d = dCol[n], s = sCol[n];
            d += __shfl_xor(d, 16); d += __shfl_xor(d, 32);
            s += __shfl_xor(s, 16); s += __shfl_xor(s, 32);
            if (l < 16) {
                atomicAdd(&denom[col0 + n * 16], d);
                atomicAdd(&Ssum[col0 + n * 16], s * INV_T);
            }
        }
    }
}

// ============ finalize ============
__global__ __launch_bounds__(1024) void finalize_kernel(const float* __restrict__ denom,
                                                        const float* __restrict__ Ssum,
                                                        const int* __restrict__ lab,
                                                        const int* __restrict__ cnt,
                                                        float* __restrict__ out) {
    const int tid = threadIdx.x;
    float lsum = 0.f, vcnt = 0.f;
    for (int r = tid; r < N; r += 1024) {
        float dsum = denom[r] - 1.0f;  // exact diagonal exp-term removal
        int P = cnt[lab[r]] - 1;
        if (P > 0) {
            float fl = (float)P;
            lsum -= (Ssum[r] - fl * logf(dsum)) / fl;
            vcnt += 1.f;
        }
    }
    __shared__ float s1[16], s2[16];
    int lane = tid & 63, wv = tid >> 6;
    #pragma unroll
    for (int m = 32; m; m >>= 1) {
        lsum += __shfl_xor(lsum, m);
        vcnt += __shfl_xor(vcnt, m);
    }
    if (lane == 0) { s1[wv] = lsum; s2[wv] = vcnt; }
    __syncthreads();
    if (wv == 0) {
        float a = (lane < 16) ? s1[lane] : 0.f;
        float b = (lane < 16) ? s2[lane] : 0.f;
        #pragma unroll
        for (int m = 8; m; m >>= 1) {
            a += __shfl_xor(a, m);
            b += __shfl_xor(b, m);
        }
        if (lane == 0) out[0] = a / fmaxf(b, 1.0f);
    }
}

// ======================================================================
// ================= fallback fp32 path (round-1, known-good) ===========
// ======================================================================
constexpr int WS_FLOATS_OLD = 12802 + 32;

__global__ __launch_bounds__(256) void rowsq_kernel(const float* __restrict__ X,
                                                    float* __restrict__ sq,
                                                    float* __restrict__ sumsq) {
    int wave = threadIdx.x >> 6;
    int lane = threadIdx.x & 63;
    int row = blockIdx.x * 4 + wave;
    const float4* p = (const float4*)(X + (size_t)row * D);
    float4 v0 = p[lane * 2];
    float4 v1 = p[lane * 2 + 1];
    float s = v0.x * v0.x + v0.y * v0.y + v0.z * v0.z + v0.w * v0.w
            + v1.x * v1.x + v1.y * v1.y + v1.z * v1.z + v1.w * v1.w;
    #pragma unroll
    for (int m = 32; m; m >>= 1) s += __shfl_xor(s, m);
    if (lane == 0) { sq[row] = s; atomicAdd(sumsq, s); }
}

__global__ __launch_bounds__(256) void colsum_kernel(const float* __restrict__ X,
                                                     float* __restrict__ colsum) {
    int c0 = threadIdx.x;
    int c1 = threadIdx.x + 256;
    int r0 = blockIdx.x * 64;
    float s0 = 0.f, s1 = 0.f;
    for (int r = r0; r < r0 + 64; r++) {
        s0 += X[(size_t)r * D + c0];
        s1 += X[(size_t)r * D + c1];
    }
    atomicAdd(&colsum[c0], s0);
    atomicAdd(&colsum[c1], s1);
}

__global__ __launch_bounds__(256) void hist_kernel(const int* __restrict__ lab,
                                                   int* __restrict__ cnt) {
    int i = blockIdx.x * 256 + threadIdx.x;
    if (i < N) atomicAdd(&cnt[lab[i]], 1);
}

__global__ __launch_bounds__(64) void bw_kernel(const float* __restrict__ colsum,
                                                const float* __restrict__ sumsq,
                                                float* __restrict__ bw) {
    int lane = threadIdx.x;
    float s = 0.f;
    for (int k = lane; k < D; k += 64) { float v = colsum[k]; s += v * v; }
    #pragma unroll
    for (int m = 32; m; m >>= 1) s += __shfl_xor(s, m);
    if (lane == 0) {
        double total = 2.0 * (double)N * (double)(*sumsq) - 2.0 * (double)s;
        double b = total / ((double)N * (double)N - (double)N);
        *bw = (float)(b / 4.0);
    }
}

constexpr int BM = 128, BN = 128, BK = 16;

__global__ __launch_bounds__(256) void gemm_fused_kernel(const float* __restrict__ X,
                                                         const int* __restrict__ lab,
                                                         const float* __restrict__ sq,
                                                         const float* __restrict__ bwp,
                                                         float* __restrict__ denom,
                                                         float* __restrict__ Ssum) {
    __shared__ float As[BK][BM];
    __shared__ float Bs[BK][BN];
    const int tid = threadIdx.x;
    const int nbx = N / BN;
    const int bx = blockIdx.x % nbx;
    const int by = blockIdx.x / nbx;
    const int rowBase = by * BM, colBase = bx * BN;
    const int lr = tid >> 1;
    const int lc = (tid & 1) * 8;
    const float* Ap = X + (size_t)(rowBase + lr) * D + lc;
    const float* Bp = X + (size_t)(colBase + lr) * D + lc;
    const int ty = tid >> 4, tx = tid & 15;

    float acc[8][8];
    #pragma unroll
    for (int i = 0; i < 8; i++)
        #pragma unroll
        for (int j = 0; j < 8; j++) acc[i][j] = 0.f;

    for (int k0 = 0; k0 < D; k0 += BK) {
        float4 a0 = *(const float4*)(Ap + k0);
        float4 a1 = *(const float4*)(Ap + k0 + 4);
        float4 b0 = *(const float4*)(Bp + k0);
        float4 b1 = *(const float4*)(Bp + k0 + 4);
        __syncthreads();
        As[lc + 0][lr] = a0.x; As[lc + 1][lr] = a0.y;
        As[lc + 2][lr] = a0.z; As[lc + 3][lr] = a0.w;
        As[lc + 4][lr] = a1.x; As[lc + 5][lr] = a1.y;
        As[lc + 6][lr] = a1.z; As[lc + 7][lr] = a1.w;
        Bs[lc + 0][lr] = b0.x; Bs[lc + 1][lr] = b0.y;
        Bs[lc + 2][lr] = b0.z; Bs[lc + 3][lr] = b0.w;
        Bs[lc + 4][lr] = b1.x; Bs[lc + 5][lr] = b1.y;
        Bs[lc + 6][lr] = b1.z; Bs[lc + 7][lr] = b1.w;
        __syncthreads();
        #pragma unroll
        for (int kk = 0; kk < BK; kk++) {
            float a[8], b[8];
            *(float4*)&a[0] = *(const float4*)&As[kk][ty * 8];
            *(float4*)&a[4] = *(const float4*)&As[kk][ty * 8 + 4];
            *(float4*)&b[0] = *(const float4*)&Bs[kk][tx * 8];
            *(float4*)&b[4] = *(const float4*)&Bs[kk][tx * 8 + 4];
            #pragma unroll
            for (int i = 0; i < 8; i++)
                #pragma unroll
                for (int j = 0; j < 8; j++)
                    acc[i][j] = fmaf(a[i], b[j], acc[i][j]);
        }
    }

    const float bw = *bwp;
    const float inv0 = 1.0f / bw;
    const float invb[5] = {inv0, inv0 * 0.5f, inv0 * 0.25f, inv0 * 0.125f, inv0 * 0.0625f};
    constexpr float INV_T = 1.0f / 0.35f;

    float sqR[8], sqC[8];
    int labR[8], labC[8];
    #pragma unroll
    for (int i = 0; i < 8; i++) {
        int r = rowBase + ty * 8 + i;
        sqR[i] = sq[r]; labR[i] = lab[r];
    }
    #pragma unroll
    for (int j = 0; j < 8; j++) {
        int c = colBase + tx * 8 + j;
        sqC[j] = sq[c]; labC[j] = lab[c];
    }

    #pragma unroll
    for (int i = 0; i < 8; i++) {
        int r = rowBase + ty * 8 + i;
        float dAcc = 0.f, sAcc = 0.f;
        #pragma unroll
        for (int j = 0; j < 8; j++) {
            int c = colBase + tx * 8 + j;
            float L2 = fmaxf(sqR[i] + sqC[j] - 2.0f * acc[i][j], 0.0f);
            float kern = 0.f;
            #pragma unroll
            for (int m = 0; m < 5; m++) kern += __expf(-L2 * invb[m]);
            float logit = (kern - 5.0f) * INV_T;
            if (r != c) {
                dAcc += __expf(logit);
                if (labR[i] == labC[j]) sAcc += logit;
            }
        }
        #pragma unroll
        for (int m = 8; m; m >>= 1) {
            dAcc += __shfl_xor(dAcc, m);
            sAcc += __shfl_xor(sAcc, m);
        }
        if (tx == 0) {
            atomicAdd(&denom[r], dAcc);
            atomicAdd(&Ssum[r], sAcc);
        }
    }
}

__global__ __launch_bounds__(1024) void finalize_old_kernel(const float* __restrict__ denom,
                                                            const float* __restrict__ Ssum,
                                                            const int* __restrict__ lab,
                                                            const int* __restrict__ cnt,
                                                            float* __restrict__ out) {
    int tid = threadIdx.x;
    float lsum = 0.f, vcnt = 0.f;
    for (int r = tid; r < N; r += 1024) {
        int P = cnt[lab[r]] - 1;
        if (P > 0) {
            float fl = (float)P;
            float mean = (Ssum[r] - fl * logf(denom[r])) / fl;
            lsum -= mean;
            vcnt += 1.f;
        }
    }
    __shared__ float s1[16], s2[16];
    int lane = tid & 63, wv = tid >> 6;
    #pragma unroll
    for (int m = 32; m; m >>= 1) {
        lsum += __shfl_xor(lsum, m);
        vcnt += __shfl_xor(vcnt, m);
    }
    if (lane == 0) { s1[wv] = lsum; s2[wv] = vcnt; }
    __syncthreads();
    if (wv == 0) {
        float a = (lane < 16) ? s1[lane] : 0.f;
        float b = (lane < 16) ? s2[lane] : 0.f;
        #pragma unroll
        for (int m = 8; m; m >>= 1) {
            a += __shfl_xor(a, m);
            b += __shfl_xor(b, m);
        }
        if (lane == 0) out[0] = a / fmaxf(b, 1.0f);
    }
}

extern "C" void kernel_launch(void* const* d_in, const int* in_sizes, int n_in,
                              void* d_out, int out_size, void* d_ws, size_t ws_size,
                              hipStream_t stream) {
    const float* X = (const float*)d_in[0];
    const int* lab = (const int*)d_in[1];
    float* ws = (float*)d_ws;

    if (ws_size >= WS_NEED) {
        u16* hi = (u16*)ws;
        float* sqh = ws + OFF_SQH;
        float* denom = ws + OFF_DEN;
        float* S = ws + OFF_S;
        float* colsum = ws + OFF_COLSUM;
        float* sumsq = ws + OFF_SUMSQ;
        int* cnt = (int*)(ws + OFF_CNT);

        hipMemsetAsync(ws + ZERO_OFF, 0, ZERO_FLOATS * sizeof(float), stream);
        prep_kernel<<<N / 16, 256, 0, stream>>>(X, lab, hi, sqh, colsum, sumsq, cnt);
        gemm_mfma_kernel<<<(32 * 33) / 2, 256, 0, stream>>>(hi, lab, sqh, colsum,
                                                            sumsq, denom, S);
        finalize_kernel<<<1, 1024, 0, stream>>>(denom, S, lab, cnt, (float*)d_out);
    } else {
        float* sq = ws;
        float* denom = ws + 4096;
        float* Ssum = ws + 8192;
        float* colsum = ws + 12288;
        float* sumsq = ws + 12800;
        float* bw = ws + 12801;
        int* cnt = (int*)(ws + 12802);

        hipMemsetAsync(d_ws, 0, WS_FLOATS_OLD * sizeof(float), stream);
        rowsq_kernel<<<N / 4, 256, 0, stream>>>(X, sq, sumsq);
        colsum_kernel<<<N / 64, 256, 0, stream>>>(X, colsum);
        hist_kernel<<<(N + 255) / 256, 256, 0, stream>>>(lab, cnt);
        bw_kernel<<<1, 64, 0, stream>>>(colsum, sumsq, bw);
        gemm_fused_kernel<<<(N / BM) * (N / BN), 256, 0, stream>>>(X, lab, sq, bw, denom, Ssum);
        finalize_old_kernel<<<1, 1024, 0, stream>>>(denom, Ssum, lab, cnt, (float*)d_out);
    }
}